// Round 4
// baseline (16705.392 us; speedup 1.0000x reference)
//
#include <hip/hip_runtime.h>
#include <hip/hip_bf16.h>
#include <hip/hip_cooperative_groups.h>
#include <cstddef>

namespace cg = cooperative_groups;

#define BB 32
#define PP 196
#define ENCD 2048
#define EMBD 512
#define DECD 512
#define ATTD 512
#define VV 10000
#define LLEN 52
#define TT 51
#define NKC 32   // k-chunks in gstep phase (2560/80)

// output offsets (floats)
#define OFF_PRED  0
#define OFF_TOKS  16320000
#define OFF_DLEN  16321664
#define OFF_ALPHA 16321696
#define OFF_SIDX  16641568

typedef __attribute__((ext_vector_type(8))) short short8;
typedef __attribute__((ext_vector_type(4))) float floatx4;

__device__ __forceinline__ float sigmf(float x) { return 1.0f / (1.0f + __expf(-x)); }
__device__ __forceinline__ unsigned short f2bf(float x) {
    __hip_bfloat16 h = __float2bfloat16(x);
    return *(unsigned short*)&h;
}
__device__ __forceinline__ float bf2f(unsigned short u) {
    unsigned int x = ((unsigned int)u) << 16;
    float f;
    __builtin_memcpy(&f, &x, 4);
    return f;
}

// ---------------------------------------------------------------- sort
__global__ void k_sort(const int* __restrict__ toks, const int* __restrict__ lens,
                       int* __restrict__ sidx, int* __restrict__ dlen, float* __restrict__ out) {
    __shared__ int s_idx[BB];
    if (threadIdx.x == 0) {
        int idx[BB], ln[BB];
        for (int i = 0; i < BB; i++) { idx[i] = i; ln[i] = lens[i]; }
        for (int i = 1; i < BB; i++) {           // stable insertion sort, descending
            int ci = idx[i], cl = ln[i]; int j = i - 1;
            while (j >= 0 && ln[j] < cl) { ln[j + 1] = ln[j]; idx[j + 1] = idx[j]; j--; }
            ln[j + 1] = cl; idx[j + 1] = ci;
        }
        for (int i = 0; i < BB; i++) {
            s_idx[i] = idx[i];
            sidx[i] = idx[i];
            int d = ln[i] - 1;
            dlen[i] = d;
            out[OFF_DLEN + i] = (float)d;
            out[OFF_SIDX + i] = (float)idx[i];
        }
    }
    __syncthreads();
    for (int i = threadIdx.x; i < BB * LLEN; i += blockDim.x) {
        int b = i / LLEN, l = i % LLEN;
        out[OFF_TOKS + i] = (float)toks[s_idx[b] * LLEN + l];
    }
}

// ---------------------------------------------------------------- mean + h0 (-> xT tail) / c0 (-> cT, k-major)
__global__ void k_init(const float* __restrict__ img, const int* __restrict__ sidx,
                       const float* __restrict__ Wh0, const float* __restrict__ bh0,
                       const float* __restrict__ Wc0, const float* __restrict__ bc0,
                       float* __restrict__ xT, float* __restrict__ cT) {
    int b = blockIdx.x;
    int sb = sidx[b];
    __shared__ float smean[ENCD];
    const float* ib = img + (size_t)sb * PP * ENCD;
    for (int e = threadIdx.x; e < ENCD; e += 256) {
        float acc = 0.f;
        for (int p = 0; p < PP; p++) acc += ib[(size_t)p * ENCD + e];
        smean[e] = acc * (1.0f / 196.0f);
    }
    __syncthreads();
    for (int d = threadIdx.x; d < DECD; d += 256) {
        const float* wh = Wh0 + (size_t)d * ENCD;
        const float* wc = Wc0 + (size_t)d * ENCD;
        float ah = bh0[d], ac = bc0[d];
        for (int e = 0; e < ENCD; e++) { float m = smean[e]; ah += m * wh[e]; ac += m * wc[e]; }
        xT[(2048 + d) * BB + b] = ah;     // hT
        cT[d * BB + b] = ac;
    }
}

// ---------------------------------------------------------------- WgT[k][gd] = k<2048 ? Wih[gd][512+k] : Whh[gd][k-2048]
__global__ void k_twg(const float* __restrict__ Wih, const float* __restrict__ Whh,
                      float* __restrict__ WgT) {
    __shared__ float sT[32][33];
    int kt = blockIdx.x, dt = blockIdx.y;
    int tx = threadIdx.x & 31, ty = threadIdx.x >> 5;  // ty 0..7
    for (int j = 0; j < 4; j++) {
        int dd = dt * 32 + ty + j * 8;
        int kk = kt * 32 + tx;
        float v = (kk < 2048) ? Wih[(size_t)dd * 2560 + 512 + kk]
                              : Whh[(size_t)dd * 512 + (kk - 2048)];
        sT[ty + j * 8][tx] = v;
    }
    __syncthreads();
    for (int j = 0; j < 4; j++) {
        int kk = kt * 32 + ty + j * 8;
        int dd = dt * 32 + tx;
        WgT[(size_t)kk * 2048 + dd] = sT[tx][ty + j * 8];
    }
}

// ---------------------------------------------------------------- WfcB: bf16 of Wfc, layout unchanged
__global__ void k_cvtfc(const float* __restrict__ Wfc, unsigned int* __restrict__ WfcB) {
    int base = (blockIdx.x * 256 + threadIdx.x) * 4;
    for (int j = 0; j < 4; j++) {
        int ui = base + j;
        const float* src = Wfc + (size_t)ui * 2;
        unsigned int lo = f2bf(src[0]), hi = f2bf(src[1]);
        WfcB[ui] = lo | (hi << 16);
    }
}

// ---------------------------------------------------------------- imgB[b][p][e] = bf16(img[sidx[b]][p][e])
__global__ void k_cvtimg(const float* __restrict__ img, const int* __restrict__ sidx,
                         unsigned int* __restrict__ imgB) {
    int row = blockIdx.x;                  // 0..6271  (b*196+p)
    int b = row / PP, p = row % PP;
    const float2* src = (const float2*)(img + ((size_t)sidx[b] * PP + p) * ENCD);
    unsigned int* dst = imgB + (size_t)row * 1024;
    for (int i = threadIdx.x; i < 1024; i += 256) {
        float2 v = src[i];
        dst[i] = f2bf(v.x) | (f2bf(v.y) << 16);
    }
}

// ---------------------------------------------------------------- encB = bf16(img_sorted @ W_enc^T + b_enc)
// M=6272, N=512, K=2048. grid (98, 4), block 256. 8x4 register tile, 64x128 block tile.
__global__ void k_enc(const float* __restrict__ img, const int* __restrict__ sidx,
                      const float* __restrict__ Wenc, const float* __restrict__ benc,
                      unsigned short* __restrict__ encB) {
    __shared__ float sA[16][68];    // [k][m]
    __shared__ float sW[16][132];   // [k][n]
    __shared__ size_t sRB[64];
    int mb = blockIdx.x, c0 = blockIdx.y * 128;
    int tid = threadIdx.x;
    int tm = tid >> 5, tn = tid & 31;
    if (tid < 64) {
        int row = mb * 64 + tid;
        int b = row / PP, p = row % PP;
        sRB[tid] = ((size_t)sidx[b] * PP + p) * ENCD;
    }
    __syncthreads();
    float acc[8][4];
#pragma unroll
    for (int i = 0; i < 8; i++)
#pragma unroll
        for (int j = 0; j < 4; j++) acc[i][j] = 0.f;

    int lcol = tid & 127, lq = tid >> 7;   // for W staging
    for (int kk = 0; kk < ENCD; kk += 16) {
        {   // A: 64 m x 16 k
            int m = tid >> 2, kq = tid & 3;
            float4 v = *(const float4*)(img + sRB[m] + kk + kq * 4);
            sA[kq * 4 + 0][m] = v.x; sA[kq * 4 + 1][m] = v.y;
            sA[kq * 4 + 2][m] = v.z; sA[kq * 4 + 3][m] = v.w;
        }
        {   // W: 128 n x 16 k
            const float* wr = Wenc + (size_t)(c0 + lcol) * ENCD + kk;
#pragma unroll
            for (int h = 0; h < 2; h++) {
                int kq = lq * 2 + h;
                float4 v = *(const float4*)(wr + kq * 4);
                sW[kq * 4 + 0][lcol] = v.x; sW[kq * 4 + 1][lcol] = v.y;
                sW[kq * 4 + 2][lcol] = v.z; sW[kq * 4 + 3][lcol] = v.w;
            }
        }
        __syncthreads();
#pragma unroll
        for (int k = 0; k < 16; k++) {
            float4 a0 = *(const float4*)&sA[k][tm * 8];
            float4 a1 = *(const float4*)&sA[k][tm * 8 + 4];
            float4 w0 = *(const float4*)&sW[k][tn * 4];
            float av[8] = {a0.x, a0.y, a0.z, a0.w, a1.x, a1.y, a1.z, a1.w};
            float wv[4] = {w0.x, w0.y, w0.z, w0.w};
#pragma unroll
            for (int i = 0; i < 8; i++)
#pragma unroll
                for (int j = 0; j < 4; j++) acc[i][j] += av[i] * wv[j];
        }
        __syncthreads();
    }
#pragma unroll
    for (int i = 0; i < 8; i++) {
        int row = mb * 64 + tm * 8 + i;
        int col = c0 + tn * 4;
        unsigned int u0 = f2bf(acc[i][0] + benc[col + 0]) | (f2bf(acc[i][1] + benc[col + 1]) << 16);
        unsigned int u1 = f2bf(acc[i][2] + benc[col + 2]) | (f2bf(acc[i][3] + benc[col + 3]) << 16);
        uint2 u = {u0, u1};
        *(uint2*)(encB + (size_t)row * ATTD + col) = u;
    }
}

// ---------------------------------------------------------------- gbaseT[t][gd][b] = emb_t @ W_ih[:, :512]^T + b_ih + b_hh
__global__ void k_gemb(const float* __restrict__ emb, const int* __restrict__ toks,
                       const int* __restrict__ sidx, const float* __restrict__ Wih,
                       const float* __restrict__ bih, const float* __restrict__ bhh,
                       float* __restrict__ gbaseT) {
    __shared__ float As[32][33];
    __shared__ float Ws[32][65];
    __shared__ size_t rb[32];
    int t = blockIdx.x, col0 = blockIdx.y * 64;
    int tid = threadIdx.x;
    int tr = tid & 31, tc = tid >> 5;
    if (tid < 32) {
        int tok = toks[sidx[tid] * LLEN + t];
        rb[tid] = (size_t)tok * EMBD;
    }
    __syncthreads();
    float acc[8] = {0, 0, 0, 0, 0, 0, 0, 0};
    for (int kk = 0; kk < EMBD; kk += 32) {
        for (int i = tid; i < 1024; i += 256) {
            int r = i >> 5, k = i & 31;
            As[r][k] = emb[rb[r] + kk + k];
        }
        for (int i = tid; i < 2048; i += 256) {
            int cc = i >> 5, k = i & 31;
            Ws[k][cc] = Wih[(size_t)(col0 + cc) * (EMBD + ENCD) + kk + k];
        }
        __syncthreads();
        for (int k = 0; k < 32; k++) {
            float a = As[tr][k];
#pragma unroll
            for (int j = 0; j < 8; j++) acc[j] += a * Ws[k][tc * 8 + j];
        }
        __syncthreads();
    }
#pragma unroll
    for (int j = 0; j < 8; j++) {
        int col = col0 + tc * 8 + j;
        gbaseT[((size_t)t * 2048 + col) * BB + tr] = acc[j] + bih[col] + bhh[col];
    }
}

// ---------------------------------------------------------------- the persistent 51-step loop (cooperative)
// grid 256 x 256. Phases: hproj -> scores -> softmax+awe+gate -> gstep -> update.
__global__ void __launch_bounds__(256) k_loop(
    const unsigned short* __restrict__ imgB,   // [b*196+p][e] bf16
    const unsigned short* __restrict__ encB,   // [b*196+p][a] bf16
    const float* __restrict__ WgT,             // [k 2560][gd 2048]
    const float* __restrict__ Wdec,            // [a 512][k 512]
    const float* __restrict__ Wbeta,           // [e 2048][k 512]
    const float* __restrict__ bdec,
    const float* __restrict__ bbeta,
    const float* __restrict__ wfull,
    const float* __restrict__ gbaseT,          // [t][gd][b]
    const int* __restrict__ dlen,
    float* __restrict__ xT,                    // [k 2560][b]; rows 2048.. = h
    float* __restrict__ hp,                    // [col 2560][b]
    float* __restrict__ scores,                // [b][200]
    float* __restrict__ gpart,                 // [kc 32][gd 2048][b]
    float* __restrict__ cT,                    // [d 512][b]
    unsigned short* __restrict__ hBT,          // [t][d 512][b] bf16
    float* __restrict__ outAlpha) {
    cg::grid_group grid = cg::this_grid();
    int blk = blockIdx.x, tid = threadIdx.x;

    __shared__ float smem[1024];               // P2: sdec[512]+swf[512]; P3: sal[256]+sred[256]

    for (int t = 0; t < TT; t++) {
        // ---- P1: hproj  hp[col][b] = sum_k W[col][k] * h[k][b]
        {
            int cl = tid >> 5, b = tid & 31;
            int colA = blk * 10 + cl;
            int colB = blk * 10 + 8 + cl;
            bool has2 = (cl < 2);
            const float* wA = (colA < 512) ? (Wdec + (size_t)colA * 512)
                                           : (Wbeta + (size_t)(colA - 512) * 512);
            const float* wB = has2 ? ((colB < 512) ? (Wdec + (size_t)colB * 512)
                                                   : (Wbeta + (size_t)(colB - 512) * 512))
                                   : wA;
            const float* xh = xT + 2048 * BB + b;
            float a0 = 0.f, a1 = 0.f, b0 = 0.f, b1 = 0.f;
            for (int k = 0; k < 512; k += 2) {
                float x0 = xh[(size_t)k * BB], x1 = xh[(size_t)(k + 1) * BB];
                a0 += wA[k] * x0; a1 += wA[k + 1] * x1;
                b0 += wB[k] * x0; b1 += wB[k + 1] * x1;
            }
            hp[(size_t)colA * BB + b] = a0 + a1;
            if (has2) hp[(size_t)colB * BB + b] = b0 + b1;
        }
        grid.sync();

        // ---- P2: scores[b][p] = sum_a relu(enc[b][p][a] + dec[a]) * w[a]
        {
            int b = blk >> 3, pc = blk & 7;
            float* sdec = smem;
            float* swf = smem + 512;
            for (int a = tid; a < 512; a += 256) {
                sdec[a] = hp[(size_t)a * BB + b] + bdec[a];
                swf[a] = wfull[a];
            }
            __syncthreads();
            int wv = tid >> 6, ln = tid & 63;
            for (int i = 0; i < 7; i++) {
                int pl = wv + i * 4;
                int p = pc * 25 + pl;
                if (pl < 25 && p < PP) {
                    const uint4* ep = (const uint4*)(encB + ((size_t)b * PP + p) * ATTD + ln * 8);
                    uint4 u = *ep;
                    float4 d0 = *(const float4*)&sdec[ln * 8];
                    float4 d1 = *(const float4*)&sdec[ln * 8 + 4];
                    float4 w0 = *(const float4*)&swf[ln * 8];
                    float4 w1 = *(const float4*)&swf[ln * 8 + 4];
                    float acc = 0.f;
                    acc += fmaxf(bf2f(u.x & 0xffff) + d0.x, 0.f) * w0.x;
                    acc += fmaxf(bf2f(u.x >> 16)    + d0.y, 0.f) * w0.y;
                    acc += fmaxf(bf2f(u.y & 0xffff) + d0.z, 0.f) * w0.z;
                    acc += fmaxf(bf2f(u.y >> 16)    + d0.w, 0.f) * w0.w;
                    acc += fmaxf(bf2f(u.z & 0xffff) + d1.x, 0.f) * w1.x;
                    acc += fmaxf(bf2f(u.z >> 16)    + d1.y, 0.f) * w1.y;
                    acc += fmaxf(bf2f(u.w & 0xffff) + d1.z, 0.f) * w1.z;
                    acc += fmaxf(bf2f(u.w >> 16)    + d1.w, 0.f) * w1.w;
                    for (int off = 32; off; off >>= 1) acc += __shfl_down(acc, off);
                    if (ln == 0) scores[b * 200 + p] = acc;
                }
            }
        }
        grid.sync();

        // ---- P3: softmax over p, write alpha; awe = alpha @ imgB; gate; -> xT[e][b]
        {
            int b = blk >> 3, ec = blk & 7;
            int e = ec * 256 + tid;
            float* sal = smem;
            float* sred = smem + 256;
            float v = (tid < PP) ? scores[b * 200 + tid] : -1e30f;
            sred[tid] = v;
            __syncthreads();
            for (int s = 128; s; s >>= 1) {
                if (tid < s) sred[tid] = fmaxf(sred[tid], sred[tid + s]);
                __syncthreads();
            }
            float mx = sred[0];
            __syncthreads();
            float ex = (tid < PP) ? __expf(v - mx) : 0.f;
            sred[tid] = ex;
            __syncthreads();
            for (int s = 128; s; s >>= 1) {
                if (tid < s) sred[tid] += sred[tid + s];
                __syncthreads();
            }
            float inv = 1.f / sred[0];
            float al = ex * inv;
            if (tid < PP) sal[tid] = al;
            if (ec == 0 && tid < PP) {
                bool active = t < dlen[b];
                outAlpha[((size_t)b * TT + t) * PP + tid] = active ? al : 0.f;
            }
            __syncthreads();
            const unsigned short* ib = imgB + (size_t)b * PP * ENCD + e;
            float acc = 0.f;
            for (int p = 0; p < PP; p++) acc += sal[p] * bf2f(ib[(size_t)p * ENCD]);
            float graw = hp[(size_t)(512 + e) * BB + b] + bbeta[e];
            xT[(size_t)e * BB + b] = acc * sigmf(graw);
        }
        grid.sync();

        // ---- P4: gstep  gpart[kc][gd][b] = sum_{k in chunk} WgT[k][gd] * xT[k][b]
        {
            int kc = blk >> 3, dg = blk & 7;
            int d = dg * 256 + tid;
            int k0 = kc * 80;
            float acc[BB];
#pragma unroll
            for (int j = 0; j < BB; j++) acc[j] = 0.f;
            const float* wp = WgT + (size_t)k0 * 2048 + d;
            const float* xp = xT + (size_t)k0 * BB;
            for (int k = 0; k < 80; k++) {
                float w = wp[(size_t)k * 2048];
                const float4* xr = (const float4*)(xp + (size_t)k * BB);
#pragma unroll
                for (int q = 0; q < 8; q++) {
                    float4 xv = xr[q];
                    acc[q * 4 + 0] += w * xv.x;
                    acc[q * 4 + 1] += w * xv.y;
                    acc[q * 4 + 2] += w * xv.z;
                    acc[q * 4 + 3] += w * xv.w;
                }
            }
            float* gp = gpart + ((size_t)kc * 2048 + d) * BB;
#pragma unroll
            for (int q = 0; q < 8; q++) {
                float4 o = {acc[q * 4 + 0], acc[q * 4 + 1], acc[q * 4 + 2], acc[q * 4 + 3]};
                *(float4*)(gp + q * 4) = o;
            }
        }
        grid.sync();

        // ---- P5: update (first 64 blocks)
        if (blk < 64) {
            int flat = blk * 256 + tid;       // 16384 = 512 d x 32 b
            int d = flat >> 5, b = flat & 31;
            bool active = t < dlen[b];
            const float* gb = gbaseT + ((size_t)t * 2048) * BB;
            float gi = gb[(size_t)d * BB + b];
            float gf = gb[(size_t)(512 + d) * BB + b];
            float gg = gb[(size_t)(1024 + d) * BB + b];
            float go = gb[(size_t)(1536 + d) * BB + b];
            for (int kc = 0; kc < NKC; kc++) {
                const float* gp = gpart + ((size_t)kc * 2048) * BB;
                gi += gp[(size_t)d * BB + b];
                gf += gp[(size_t)(512 + d) * BB + b];
                gg += gp[(size_t)(1024 + d) * BB + b];
                go += gp[(size_t)(1536 + d) * BB + b];
            }
            float i_ = sigmf(gi), f_ = sigmf(gf), g_ = tanhf(gg), o_ = sigmf(go);
            float cv = cT[(size_t)d * BB + b];
            float cn = f_ * cv + i_ * g_;
            float hn = o_ * tanhf(cn);
            float hv;
            if (active) {
                cT[(size_t)d * BB + b] = cn;
                xT[(size_t)(2048 + d) * BB + b] = hn;
                hv = hn;
            } else {
                hv = xT[(size_t)(2048 + d) * BB + b];
            }
            hBT[((size_t)t * 512 + d) * BB + b] = f2bf(hv);
        }
        grid.sync();
    }
}

// ---------------------------------------------------------------- predictions via bf16 MFMA
// C[m=32 b][n=10000] per t; grid (51, 40), block 256 (4 waves).
__global__ void k_pred(const unsigned short* __restrict__ hBT, const unsigned short* __restrict__ WfcB,
                       const float* __restrict__ bfc, const int* __restrict__ dlen,
                       float* __restrict__ out) {
    __shared__ unsigned short sA[32 * 40];   // [m][k], row stride 40 shorts
    __shared__ unsigned short sB[256 * 40];  // [n][k]
    int t = blockIdx.x, n0 = blockIdx.y * 256;
    int tid = threadIdx.x;
    int wv = tid >> 6, lane = tid & 63;
    int quad = lane >> 4, l16 = lane & 15;

    floatx4 acc[2][4];
#pragma unroll
    for (int i = 0; i < 2; i++)
#pragma unroll
        for (int j = 0; j < 4; j++) acc[i][j] = (floatx4){0.f, 0.f, 0.f, 0.f};

    for (int kk = 0; kk < 512; kk += 32) {
        // stage A: from hBT[t][k][m]: transpose into sA[m][k]
        for (int j = 0; j < 2; j++) {
            int u = tid + j * 256;            // 0..511
            int k = u >> 4, mp = u & 15;      // mp -> m pair
            unsigned int v = *(const unsigned int*)(hBT + ((size_t)t * 512 + kk + k) * BB + mp * 2);
            sA[(mp * 2) * 40 + k] = (unsigned short)(v & 0xffff);
            sA[(mp * 2 + 1) * 40 + k] = (unsigned short)(v >> 16);
        }
        // stage B: 256 n x 32 k
        {
            unsigned int* dst = (unsigned int*)sB;
#pragma unroll
            for (int j = 0; j < 16; j++) {
                int idx = tid + j * 256;
                int n = idx >> 4, kp = idx & 15;
                int gn = n0 + n;
                unsigned int v = 0u;
                if (gn < VV) v = ((const unsigned int*)(WfcB + (size_t)gn * 512 + kk))[kp];
                dst[n * 20 + kp] = v;
            }
        }
        __syncthreads();
        short8 af[2], bf[4];
#pragma unroll
        for (int mt = 0; mt < 2; mt++)
            af[mt] = *(const short8*)(sA + (mt * 16 + l16) * 40 + quad * 8);
#pragma unroll
        for (int nt = 0; nt < 4; nt++) {
            int nl = wv * 64 + nt * 16 + l16;
            bf[nt] = *(const short8*)(sB + nl * 40 + quad * 8);
        }
#pragma unroll
        for (int mt = 0; mt < 2; mt++)
#pragma unroll
            for (int nt = 0; nt < 4; nt++)
                acc[mt][nt] = __builtin_amdgcn_mfma_f32_16x16x32_bf16(af[mt], bf[nt], acc[mt][nt], 0, 0, 0);
        __syncthreads();
    }
#pragma unroll
    for (int mt = 0; mt < 2; mt++) {
#pragma unroll
        for (int r = 0; r < 4; r++) {
            int m = mt * 16 + quad * 4 + r;   // = b
            bool active = t < dlen[m];
            float* orow = out + OFF_PRED + ((size_t)m * TT + t) * VV;
#pragma unroll
            for (int nt = 0; nt < 4; nt++) {
                int n = n0 + wv * 64 + nt * 16 + l16;
                if (n < VV) orow[n] = active ? (acc[mt][nt][r] + bfc[n]) : 0.f;
            }
        }
    }
}

// ---------------------------------------------------------------- launch
extern "C" void kernel_launch(void* const* d_in, const int* in_sizes, int n_in,
                              void* d_out, int out_size, void* d_ws, size_t ws_size,
                              hipStream_t stream) {
    const float* img   = (const float*)d_in[0];
    const int*   toks  = (const int*)d_in[1];
    const int*   lens  = (const int*)d_in[2];
    const float* Wenc  = (const float*)d_in[3];
    const float* benc  = (const float*)d_in[4];
    const float* Wdec  = (const float*)d_in[5];
    const float* bdec  = (const float*)d_in[6];
    const float* wfull = (const float*)d_in[7];
    // d_in[8] = b_full (scalar 0; softmax-invariant)
    const float* emb   = (const float*)d_in[9];
    const float* Wih   = (const float*)d_in[10];
    const float* bih   = (const float*)d_in[11];
    const float* Whh   = (const float*)d_in[12];
    const float* bhh   = (const float*)d_in[13];
    const float* Wh0   = (const float*)d_in[14];
    const float* bh0   = (const float*)d_in[15];
    const float* Wc0   = (const float*)d_in[16];
    const float* bc0   = (const float*)d_in[17];
    const float* Wbeta = (const float*)d_in[18];
    const float* bbeta = (const float*)d_in[19];
    const float* Wfc   = (const float*)d_in[20];
    const float* bfc   = (const float*)d_in[21];
    float* out = (float*)d_out;

    // workspace layout
    char* ws = (char*)d_ws;
    int* sidx = (int*)ws;                     ws += 256;
    int* dlen = (int*)ws;                     ws += 256;
    float* cT       = (float*)ws;             ws += (size_t)DECD * BB * 4;          // 64 KB
    float* xT       = (float*)ws;             ws += (size_t)2560 * BB * 4;          // 320 KB
    float* hp       = (float*)ws;             ws += (size_t)2560 * BB * 4;          // 320 KB
    float* scores   = (float*)ws;             ws += (size_t)BB * 200 * 4;           // 25.6 KB
    float* gpart    = (float*)ws;             ws += (size_t)NKC * 2048 * BB * 4;    // 8 MB
    unsigned short* hBT = (unsigned short*)ws; ws += (size_t)TT * DECD * BB * 2;    // 1.67 MB
    float* WgT      = (float*)ws;             ws += (size_t)2560 * 2048 * 4;        // 21 MB
    unsigned int* WfcB = (unsigned int*)ws;   ws += (size_t)VV * 512 * 2;           // 10.24 MB
    unsigned int* imgB = (unsigned int*)ws;   ws += (size_t)BB * PP * ENCD * 2;     // 25.7 MB
    unsigned short* encB = (unsigned short*)ws; ws += (size_t)BB * PP * ATTD * 2;   // 6.4 MB
    float* gbaseT   = (float*)ws;             ws += (size_t)TT * 2048 * BB * 4;     // 13.4 MB

    k_sort<<<1, 64, 0, stream>>>(toks, lens, sidx, dlen, out);
    k_init<<<32, 256, 0, stream>>>(img, sidx, Wh0, bh0, Wc0, bc0, xT, cT);
    k_twg<<<dim3(80, 64), 256, 0, stream>>>(Wih, Whh, WgT);
    k_cvtfc<<<2500, 256, 0, stream>>>(Wfc, WfcB);
    k_cvtimg<<<6272, 256, 0, stream>>>(img, sidx, imgB);
    k_enc<<<dim3(98, 4), 256, 0, stream>>>(img, sidx, Wenc, benc, encB);
    k_gemb<<<dim3(51, 32), 256, 0, stream>>>(emb, toks, sidx, Wih, bih, bhh, gbaseT);

    {
        const unsigned short* a_imgB = (const unsigned short*)imgB;
        const unsigned short* a_encB = encB;
        const float* a_WgT = WgT;
        const float* a_Wdec = Wdec;
        const float* a_Wbeta = Wbeta;
        const float* a_bdec = bdec;
        const float* a_bbeta = bbeta;
        const float* a_wfull = wfull;
        const float* a_gbaseT = gbaseT;
        const int* a_dlen = dlen;
        float* a_xT = xT;
        float* a_hp = hp;
        float* a_scores = scores;
        float* a_gpart = gpart;
        float* a_cT = cT;
        unsigned short* a_hBT = hBT;
        float* a_outAlpha = out + OFF_ALPHA;
        void* kargs[] = {
            (void*)&a_imgB, (void*)&a_encB, (void*)&a_WgT, (void*)&a_Wdec,
            (void*)&a_Wbeta, (void*)&a_bdec, (void*)&a_bbeta, (void*)&a_wfull,
            (void*)&a_gbaseT, (void*)&a_dlen, (void*)&a_xT, (void*)&a_hp,
            (void*)&a_scores, (void*)&a_gpart, (void*)&a_cT, (void*)&a_hBT,
            (void*)&a_outAlpha
        };
        hipLaunchCooperativeKernel((void*)k_loop, dim3(256), dim3(256), kargs, 0, stream);
    }

    k_pred<<<dim3(TT, 40), 256, 0, stream>>>(hBT, (const unsigned short*)WfcB, bfc, dlen, out);
}

// Round 5
// 7759.796 us; speedup vs baseline: 2.1528x; 2.1528x over previous
//
#include <hip/hip_runtime.h>
#include <hip/hip_bf16.h>
#include <cstddef>

#define BB 32
#define PP 196
#define ENCD 2048
#define EMBD 512
#define DECD 512
#define ATTD 512
#define VV 10000
#define LLEN 52
#define TT 51

// output offsets (floats)
#define OFF_PRED  0
#define OFF_TOKS  16320000
#define OFF_DLEN  16321664
#define OFF_ALPHA 16321696
#define OFF_SIDX  16641568

#define AGENT __HIP_MEMORY_SCOPE_AGENT

typedef __attribute__((ext_vector_type(8))) short short8;
typedef __attribute__((ext_vector_type(4))) float floatx4;

__device__ __forceinline__ float sigmf(float x) { return 1.0f / (1.0f + __expf(-x)); }
__device__ __forceinline__ unsigned short f2bf(float x) {
    __hip_bfloat16 h = __float2bfloat16(x);
    return *(unsigned short*)&h;
}
__device__ __forceinline__ float bf2f(unsigned int u) {
    unsigned int x = u << 16;
    float f;
    __builtin_memcpy(&f, &x, 4);
    return f;
}
__device__ __forceinline__ void ast(float* p, float v) {
    __hip_atomic_store(p, v, __ATOMIC_RELAXED, AGENT);
}
__device__ __forceinline__ float ald(const float* p) {
    return __hip_atomic_load(p, __ATOMIC_RELAXED, AGENT);
}

// ---------------------------------------------------------------- sort (+ zero counters)
__global__ void k_sort(const int* __restrict__ toks, const int* __restrict__ lens,
                       int* __restrict__ sidx, int* __restrict__ dlen, int* __restrict__ cnt,
                       float* __restrict__ out) {
    __shared__ int s_idx[BB];
    if (threadIdx.x < 40) cnt[threadIdx.x] = 0;
    if (threadIdx.x == 0) {
        int idx[BB], ln[BB];
        for (int i = 0; i < BB; i++) { idx[i] = i; ln[i] = lens[i]; }
        for (int i = 1; i < BB; i++) {           // stable insertion sort, descending
            int ci = idx[i], cl = ln[i]; int j = i - 1;
            while (j >= 0 && ln[j] < cl) { ln[j + 1] = ln[j]; idx[j + 1] = idx[j]; j--; }
            ln[j + 1] = cl; idx[j + 1] = ci;
        }
        for (int i = 0; i < BB; i++) {
            s_idx[i] = idx[i];
            sidx[i] = idx[i];
            int d = ln[i] - 1;
            dlen[i] = d;
            out[OFF_DLEN + i] = (float)d;
            out[OFF_SIDX + i] = (float)idx[i];
        }
    }
    __syncthreads();
    for (int i = threadIdx.x; i < BB * LLEN; i += blockDim.x) {
        int b = i / LLEN, l = i % LLEN;
        out[OFF_TOKS + i] = (float)toks[s_idx[b] * LLEN + l];
    }
}

// ---------------------------------------------------------------- mean + h0 (-> xT tail) / c0 (-> cT)
__global__ void k_init(const float* __restrict__ img, const int* __restrict__ sidx,
                       const float* __restrict__ Wh0, const float* __restrict__ bh0,
                       const float* __restrict__ Wc0, const float* __restrict__ bc0,
                       float* __restrict__ xT, float* __restrict__ cT) {
    int b = blockIdx.x;
    int sb = sidx[b];
    __shared__ float smean[ENCD];
    const float* ib = img + (size_t)sb * PP * ENCD;
    for (int e = threadIdx.x; e < ENCD; e += 256) {
        float acc = 0.f;
        for (int p = 0; p < PP; p++) acc += ib[(size_t)p * ENCD + e];
        smean[e] = acc * (1.0f / 196.0f);
    }
    __syncthreads();
    for (int d = threadIdx.x; d < DECD; d += 256) {
        const float* wh = Wh0 + (size_t)d * ENCD;
        const float* wc = Wc0 + (size_t)d * ENCD;
        float ah = bh0[d], ac = bc0[d];
        for (int e = 0; e < ENCD; e++) { float m = smean[e]; ah += m * wh[e]; ac += m * wc[e]; }
        xT[(2048 + d) * BB + b] = ah;
        cT[d * BB + b] = ac;
    }
}

// ---------------------------------------------------------------- bf16 converters
__global__ void k_cvt4(const float* __restrict__ src, unsigned int* __restrict__ dst) {
    int base = (blockIdx.x * 256 + threadIdx.x) * 4;
    for (int j = 0; j < 4; j++) {
        int ui = base + j;
        const float* s = src + (size_t)ui * 2;
        dst[ui] = f2bf(s[0]) | ((unsigned int)f2bf(s[1]) << 16);
    }
}

__global__ void k_cvthp(const float* __restrict__ Wdec, const float* __restrict__ Wbeta,
                        unsigned int* __restrict__ WhpB) {
    int r = blockIdx.x;
    const float* src = (r < 512) ? (Wdec + (size_t)r * 512) : (Wbeta + (size_t)(r - 512) * 512);
    int t2 = threadIdx.x;
    WhpB[(size_t)r * 256 + t2] = f2bf(src[t2 * 2]) | ((unsigned int)f2bf(src[t2 * 2 + 1]) << 16);
}

__global__ void k_cvtwih(const float* __restrict__ Wih, unsigned int* __restrict__ WihB) {
    int r = blockIdx.x;
    const float* src = Wih + (size_t)r * 2560;
    int t2 = threadIdx.x;
    WihB[(size_t)r * 256 + t2] = f2bf(src[t2 * 2]) | ((unsigned int)f2bf(src[t2 * 2 + 1]) << 16);
}

__global__ void k_cvtimg(const float* __restrict__ img, const int* __restrict__ sidx,
                         unsigned int* __restrict__ imgB) {
    int row = blockIdx.x;
    int b = row / PP, p = row % PP;
    const float2* src = (const float2*)(img + ((size_t)sidx[b] * PP + p) * ENCD);
    unsigned int* dst = imgB + (size_t)row * 1024;
    for (int i = threadIdx.x; i < 1024; i += 256) {
        float2 v = src[i];
        dst[i] = f2bf(v.x) | ((unsigned int)f2bf(v.y) << 16);
    }
}

__global__ void k_twgb(const float* __restrict__ Wih, const float* __restrict__ Whh,
                       unsigned short* __restrict__ WgB) {
    __shared__ float sT[32][33];
    int kt = blockIdx.x, dt = blockIdx.y;
    int tx = threadIdx.x & 31, ty = threadIdx.x >> 5;
    for (int j = 0; j < 4; j++) {
        int dd = dt * 32 + ty + j * 8;
        int kk = kt * 32 + tx;
        float v = (kk < 2048) ? Wih[(size_t)dd * 2560 + 512 + kk]
                              : Whh[(size_t)dd * 512 + (kk - 2048)];
        sT[ty + j * 8][tx] = v;
    }
    __syncthreads();
    for (int j = 0; j < 4; j++) {
        int kk = kt * 32 + ty + j * 8;
        int dd = dt * 32 + tx;
        WgB[(size_t)kk * 2048 + dd] = f2bf(sT[tx][ty + j * 8]);
    }
}

// ---------------------------------------------------------------- encB = bf16(imgB @ WencB^T + benc), MFMA
__global__ void k_genc(const unsigned short* __restrict__ imgB, const unsigned short* __restrict__ WencB,
                       const float* __restrict__ benc, unsigned short* __restrict__ encB) {
    __shared__ unsigned short sA[32 * 40];
    __shared__ unsigned short sB[256 * 40];
    int m0 = blockIdx.x * 32, n0 = blockIdx.y * 256;
    int tid = threadIdx.x;
    int wv = tid >> 6, lane = tid & 63;
    int quad = lane >> 4, l16 = lane & 15;
    floatx4 acc[2][4];
#pragma unroll
    for (int i = 0; i < 2; i++)
#pragma unroll
        for (int j = 0; j < 4; j++) acc[i][j] = (floatx4){0.f, 0.f, 0.f, 0.f};

    for (int kk = 0; kk < ENCD; kk += 32) {
        if (tid < 128) {
            int m = tid >> 2, kc8 = tid & 3;
            uint4 v = *(const uint4*)(imgB + (size_t)(m0 + m) * ENCD + kk + kc8 * 8);
            *(uint4*)(sA + m * 40 + kc8 * 8) = v;
        }
        {
            unsigned int* dst = (unsigned int*)sB;
#pragma unroll
            for (int j = 0; j < 16; j++) {
                int idx = tid + j * 256;
                int n = idx >> 4, kp = idx & 15;
                dst[n * 20 + kp] = ((const unsigned int*)(WencB + (size_t)(n0 + n) * ENCD + kk))[kp];
            }
        }
        __syncthreads();
        short8 af[2], bf[4];
#pragma unroll
        for (int mt = 0; mt < 2; mt++)
            af[mt] = *(const short8*)(sA + (mt * 16 + l16) * 40 + quad * 8);
#pragma unroll
        for (int nt = 0; nt < 4; nt++) {
            int nl = wv * 64 + nt * 16 + l16;
            bf[nt] = *(const short8*)(sB + nl * 40 + quad * 8);
        }
#pragma unroll
        for (int mt = 0; mt < 2; mt++)
#pragma unroll
            for (int nt = 0; nt < 4; nt++)
                acc[mt][nt] = __builtin_amdgcn_mfma_f32_16x16x32_bf16(af[mt], bf[nt], acc[mt][nt], 0, 0, 0);
        __syncthreads();
    }
#pragma unroll
    for (int mt = 0; mt < 2; mt++) {
#pragma unroll
        for (int r = 0; r < 4; r++) {
            int row = m0 + mt * 16 + quad * 4 + r;
#pragma unroll
            for (int nt = 0; nt < 4; nt++) {
                int n = n0 + wv * 64 + nt * 16 + l16;
                encB[(size_t)row * ATTD + n] = f2bf(acc[mt][nt][r] + benc[n]);
            }
        }
    }
}

// ---------------------------------------------------------------- gbase[t][b][gd] (MFMA); t==0 also seeds gacc
__global__ void k_gemb(const unsigned short* __restrict__ embB, const int* __restrict__ toks,
                       const int* __restrict__ sidx, const unsigned short* __restrict__ WihB,
                       const float* __restrict__ bih, const float* __restrict__ bhh,
                       float* __restrict__ gbase, float* __restrict__ gacc) {
    __shared__ unsigned short sA[32 * 40];
    __shared__ unsigned short sB[256 * 40];
    __shared__ size_t rb[32];
    int t = blockIdx.x, n0 = blockIdx.y * 256;
    int tid = threadIdx.x;
    int wv = tid >> 6, lane = tid & 63;
    int quad = lane >> 4, l16 = lane & 15;
    if (tid < 32) rb[tid] = (size_t)toks[sidx[tid] * LLEN + t] * EMBD;
    __syncthreads();
    floatx4 acc[2][4];
#pragma unroll
    for (int i = 0; i < 2; i++)
#pragma unroll
        for (int j = 0; j < 4; j++) acc[i][j] = (floatx4){0.f, 0.f, 0.f, 0.f};

    for (int kk = 0; kk < EMBD; kk += 32) {
        if (tid < 128) {
            int m = tid >> 2, kc8 = tid & 3;
            uint4 v = *(const uint4*)(embB + rb[m] + kk + kc8 * 8);
            *(uint4*)(sA + m * 40 + kc8 * 8) = v;
        }
        {
            unsigned int* dst = (unsigned int*)sB;
#pragma unroll
            for (int j = 0; j < 16; j++) {
                int idx = tid + j * 256;
                int n = idx >> 4, kp = idx & 15;
                dst[n * 20 + kp] = ((const unsigned int*)(WihB + (size_t)(n0 + n) * EMBD + kk))[kp];
            }
        }
        __syncthreads();
        short8 af[2], bf[4];
#pragma unroll
        for (int mt = 0; mt < 2; mt++)
            af[mt] = *(const short8*)(sA + (mt * 16 + l16) * 40 + quad * 8);
#pragma unroll
        for (int nt = 0; nt < 4; nt++) {
            int nl = wv * 64 + nt * 16 + l16;
            bf[nt] = *(const short8*)(sB + nl * 40 + quad * 8);
        }
#pragma unroll
        for (int mt = 0; mt < 2; mt++)
#pragma unroll
            for (int nt = 0; nt < 4; nt++)
                acc[mt][nt] = __builtin_amdgcn_mfma_f32_16x16x32_bf16(af[mt], bf[nt], acc[mt][nt], 0, 0, 0);
        __syncthreads();
    }
#pragma unroll
    for (int mt = 0; mt < 2; mt++) {
#pragma unroll
        for (int r = 0; r < 4; r++) {
            int m = mt * 16 + quad * 4 + r;   // = b
#pragma unroll
            for (int nt = 0; nt < 4; nt++) {
                int n = n0 + wv * 64 + nt * 16 + l16;
                float v = acc[mt][nt][r] + bih[n] + bhh[n];
                gbase[((size_t)t * BB + m) * 2048 + n] = v;
                if (t == 0) gacc[(size_t)m * 2048 + n] = v;
            }
        }
    }
}

// ---------------------------------------------------------------- K1: hp[col][b]
__global__ void k_hproj(const unsigned int* __restrict__ WhpB, const float* __restrict__ xT,
                        float* __restrict__ hp) {
    int tid = threadIdx.x;
    int cl = tid >> 5, b = tid & 31;
    int c0 = blockIdx.x * 10;
    int colA = c0 + cl;
    int colB = c0 + 8 + cl;
    bool has2 = (cl < 2);
    const uint4* pA = (const uint4*)(WhpB + (size_t)colA * 256);
    const uint4* pB = (const uint4*)(WhpB + (size_t)(has2 ? colB : colA) * 256);
    const float* xh = xT + 2048 * BB + b;
    float aA = 0.f, aB = 0.f;
    for (int kb = 0; kb < 64; kb++) {
        uint4 wa = pA[kb];
        uint4 wb = pB[kb];
        float x0 = xh[(size_t)(kb * 8 + 0) * BB], x1 = xh[(size_t)(kb * 8 + 1) * BB];
        float x2 = xh[(size_t)(kb * 8 + 2) * BB], x3 = xh[(size_t)(kb * 8 + 3) * BB];
        float x4 = xh[(size_t)(kb * 8 + 4) * BB], x5 = xh[(size_t)(kb * 8 + 5) * BB];
        float x6 = xh[(size_t)(kb * 8 + 6) * BB], x7 = xh[(size_t)(kb * 8 + 7) * BB];
        aA += bf2f(wa.x & 0xffff) * x0 + bf2f(wa.x >> 16) * x1
            + bf2f(wa.y & 0xffff) * x2 + bf2f(wa.y >> 16) * x3
            + bf2f(wa.z & 0xffff) * x4 + bf2f(wa.z >> 16) * x5
            + bf2f(wa.w & 0xffff) * x6 + bf2f(wa.w >> 16) * x7;
        aB += bf2f(wb.x & 0xffff) * x0 + bf2f(wb.x >> 16) * x1
            + bf2f(wb.y & 0xffff) * x2 + bf2f(wb.y >> 16) * x3
            + bf2f(wb.z & 0xffff) * x4 + bf2f(wb.z >> 16) * x5
            + bf2f(wb.w & 0xffff) * x6 + bf2f(wb.w >> 16) * x7;
    }
    hp[(size_t)colA * BB + b] = aA;
    if (has2) hp[(size_t)colB * BB + b] = aB;
}

// ---------------------------------------------------------------- K2: scores + partial awe; last block per b merges
__global__ void k_attn(int t, const unsigned short* __restrict__ imgB,
                       const unsigned short* __restrict__ encB, const float* __restrict__ hp,
                       const float* __restrict__ bdec, const float* __restrict__ bbeta,
                       const float* __restrict__ wfull, const int* __restrict__ dlen,
                       float* __restrict__ s_ws, float* __restrict__ mz_ws,
                       float* __restrict__ pawe, float* __restrict__ xT,
                       int* __restrict__ cnt_b, float* __restrict__ outAlpha) {
    int b = blockIdx.x >> 3, pc = blockIdx.x & 7;
    int tid = threadIdx.x;
    int p0 = pc * 25;
    int np = (PP - p0 < 25) ? (PP - p0) : 25;
    __shared__ float sdec[512], swf[512], sS[32], sE[32];
    __shared__ int isLast;
    for (int a = tid; a < 512; a += 256) {
        sdec[a] = hp[(size_t)a * BB + b] + bdec[a];
        swf[a] = wfull[a];
    }
    __syncthreads();
    int wv = tid >> 6, ln = tid & 63;
    for (int i = 0; i < 7; i++) {
        int pl = wv + i * 4;
        if (pl < np) {
            int p = p0 + pl;
            uint4 u = *(const uint4*)(encB + ((size_t)(b * PP + p)) * ATTD + ln * 8);
            float4 d0 = *(const float4*)&sdec[ln * 8];
            float4 d1 = *(const float4*)&sdec[ln * 8 + 4];
            float4 w0 = *(const float4*)&swf[ln * 8];
            float4 w1 = *(const float4*)&swf[ln * 8 + 4];
            float acc = 0.f;
            acc += fmaxf(bf2f(u.x & 0xffff) + d0.x, 0.f) * w0.x;
            acc += fmaxf(bf2f(u.x >> 16)    + d0.y, 0.f) * w0.y;
            acc += fmaxf(bf2f(u.y & 0xffff) + d0.z, 0.f) * w0.z;
            acc += fmaxf(bf2f(u.y >> 16)    + d0.w, 0.f) * w0.w;
            acc += fmaxf(bf2f(u.z & 0xffff) + d1.x, 0.f) * w1.x;
            acc += fmaxf(bf2f(u.z >> 16)    + d1.y, 0.f) * w1.y;
            acc += fmaxf(bf2f(u.w & 0xffff) + d1.z, 0.f) * w1.z;
            acc += fmaxf(bf2f(u.w >> 16)    + d1.w, 0.f) * w1.w;
            for (int off = 32; off; off >>= 1) acc += __shfl_down(acc, off);
            if (ln == 0) sS[pl] = acc;
        }
    }
    __syncthreads();
    float m = -1e30f;
    for (int i = 0; i < np; i++) m = fmaxf(m, sS[i]);
    if (tid < np) sE[tid] = __expf(sS[tid] - m);
    __syncthreads();
    float z = 0.f;
    for (int i = 0; i < np; i++) z += sE[i];
    float a8[8] = {0, 0, 0, 0, 0, 0, 0, 0};
    const unsigned short* ib = imgB + ((size_t)(b * PP + p0)) * ENCD + tid * 8;
    for (int p = 0; p < np; p++) {
        float w = sE[p];
        uint4 v = *(const uint4*)(ib + (size_t)p * ENCD);
        a8[0] += w * bf2f(v.x & 0xffff); a8[1] += w * bf2f(v.x >> 16);
        a8[2] += w * bf2f(v.y & 0xffff); a8[3] += w * bf2f(v.y >> 16);
        a8[4] += w * bf2f(v.z & 0xffff); a8[5] += w * bf2f(v.z >> 16);
        a8[6] += w * bf2f(v.w & 0xffff); a8[7] += w * bf2f(v.w >> 16);
    }
    float* pw = pawe + ((size_t)(b * 8 + pc)) * 2048 + tid * 8;
#pragma unroll
    for (int j = 0; j < 8; j++) ast(pw + j, a8[j]);
    if (tid < np) ast(&s_ws[b * 200 + p0 + tid], sS[tid]);
    if (tid == 0) { ast(&mz_ws[(b * 8 + pc) * 2], m); ast(&mz_ws[(b * 8 + pc) * 2 + 1], z); }
    __threadfence();
    __syncthreads();
    if (tid == 0) {
        int r = __hip_atomic_fetch_add(&cnt_b[b], 1, __ATOMIC_ACQ_REL, AGENT);
        isLast = (r == 7);
        if (isLast) __hip_atomic_store(&cnt_b[b], 0, __ATOMIC_RELAXED, AGENT);
    }
    __syncthreads();
    if (!isLast) return;
    float mm[8], zz[8];
#pragma unroll
    for (int i = 0; i < 8; i++) {
        mm[i] = ald(&mz_ws[(b * 8 + i) * 2]);
        zz[i] = ald(&mz_ws[(b * 8 + i) * 2 + 1]);
    }
    float M = mm[0];
#pragma unroll
    for (int i = 1; i < 8; i++) M = fmaxf(M, mm[i]);
    float Z = 0.f;
    float sc[8];
#pragma unroll
    for (int i = 0; i < 8; i++) { sc[i] = __expf(mm[i] - M); Z += zz[i] * sc[i]; }
    float invZ = 1.f / Z;
    bool active = t < dlen[b];
    if (tid < PP) {
        float s = ald(&s_ws[b * 200 + tid]);
        float al = __expf(s - M) * invZ;
        outAlpha[((size_t)b * TT + t) * PP + tid] = active ? al : 0.f;
    }
#pragma unroll
    for (int i = 0; i < 8; i++) sc[i] *= invZ;
    for (int j = 0; j < 8; j++) {
        int e = tid + j * 256;
        float acc = 0.f;
#pragma unroll
        for (int i = 0; i < 8; i++) acc += ald(&pawe[((size_t)(b * 8 + i)) * 2048 + e]) * sc[i];
        float graw = hp[(size_t)(512 + e) * BB + b] + bbeta[e];
        xT[(size_t)e * BB + b] = acc * sigmf(graw);
    }
}

// ---------------------------------------------------------------- K3: gate partials (atomicAdd) + LSTM update
__global__ void k_gstep(int t, const unsigned short* __restrict__ WgB, float* __restrict__ xT,
                        const float* __restrict__ gbase, float* __restrict__ gacc,
                        float* __restrict__ cT, unsigned short* __restrict__ hBT,
                        const int* __restrict__ dlen, int* __restrict__ cnt_g) {
    int tid = threadIdx.x;
    int kc = blockIdx.x & 31, dg = blockIdx.x >> 5;
    int d = dg * 256 + tid;
    int k0 = kc * 80;
    float acc[BB];
#pragma unroll
    for (int j = 0; j < BB; j++) acc[j] = 0.f;
    const unsigned short* wp = WgB + (size_t)k0 * 2048 + d;
    const float* xp = xT + (size_t)k0 * BB;
    for (int k = 0; k < 80; k++) {
        float w = bf2f(wp[(size_t)k * 2048]);
        const float4* xr = (const float4*)(xp + (size_t)k * BB);
#pragma unroll
        for (int q = 0; q < 8; q++) {
            float4 xv = xr[q];
            acc[q * 4 + 0] += w * xv.x;
            acc[q * 4 + 1] += w * xv.y;
            acc[q * 4 + 2] += w * xv.z;
            acc[q * 4 + 3] += w * xv.w;
        }
    }
#pragma unroll
    for (int b2 = 0; b2 < BB; b2++) unsafeAtomicAdd(&gacc[(size_t)b2 * 2048 + d], acc[b2]);
    __threadfence();
    __syncthreads();
    __shared__ int isLast;
    if (tid == 0) {
        int g = dg & 1;
        int r = __hip_atomic_fetch_add(&cnt_g[g], 1, __ATOMIC_ACQ_REL, AGENT);
        isLast = (r == 127);
        if (isLast) __hip_atomic_store(&cnt_g[g], 0, __ATOMIC_RELAXED, AGENT);
    }
    __syncthreads();
    if (!isLast) return;
    int dc = (dg & 1) * 256 + tid;
    for (int b2 = 0; b2 < BB; b2++) {
        float gi = ald(&gacc[(size_t)b2 * 2048 + dc]);
        float gf = ald(&gacc[(size_t)b2 * 2048 + 512 + dc]);
        float gg = ald(&gacc[(size_t)b2 * 2048 + 1024 + dc]);
        float go = ald(&gacc[(size_t)b2 * 2048 + 1536 + dc]);
        float i_ = sigmf(gi), f_ = sigmf(gf), g_ = tanhf(gg), o_ = sigmf(go);
        float cv = cT[(size_t)dc * BB + b2];
        float cn = f_ * cv + i_ * g_;
        float hn = o_ * tanhf(cn);
        bool active = t < dlen[b2];
        float hv;
        if (active) {
            cT[(size_t)dc * BB + b2] = cn;
            xT[(size_t)(2048 + dc) * BB + b2] = hn;
            hv = hn;
        } else {
            hv = xT[(size_t)(2048 + dc) * BB + b2];
        }
        hBT[((size_t)t * 512 + dc) * BB + b2] = f2bf(hv);
        if (t + 1 < TT) {
            const float* gb = gbase + ((size_t)(t + 1) * BB + b2) * 2048;
            gacc[(size_t)b2 * 2048 + dc] = gb[dc];
            gacc[(size_t)b2 * 2048 + 512 + dc] = gb[512 + dc];
            gacc[(size_t)b2 * 2048 + 1024 + dc] = gb[1024 + dc];
            gacc[(size_t)b2 * 2048 + 1536 + dc] = gb[1536 + dc];
        }
    }
}

// ---------------------------------------------------------------- predictions via bf16 MFMA
__global__ void k_pred(const unsigned short* __restrict__ hBT, const unsigned short* __restrict__ WfcB,
                       const float* __restrict__ bfc, const int* __restrict__ dlen,
                       float* __restrict__ out) {
    __shared__ unsigned short sA[32 * 40];
    __shared__ unsigned short sB[256 * 40];
    int t = blockIdx.x, n0 = blockIdx.y * 256;
    int tid = threadIdx.x;
    int wv = tid >> 6, lane = tid & 63;
    int quad = lane >> 4, l16 = lane & 15;

    floatx4 acc[2][4];
#pragma unroll
    for (int i = 0; i < 2; i++)
#pragma unroll
        for (int j = 0; j < 4; j++) acc[i][j] = (floatx4){0.f, 0.f, 0.f, 0.f};

    for (int kk = 0; kk < 512; kk += 32) {
        for (int j = 0; j < 2; j++) {
            int u = tid + j * 256;
            int k = u >> 4, mp = u & 15;
            unsigned int v = *(const unsigned int*)(hBT + ((size_t)t * 512 + kk + k) * BB + mp * 2);
            sA[(mp * 2) * 40 + k] = (unsigned short)(v & 0xffff);
            sA[(mp * 2 + 1) * 40 + k] = (unsigned short)(v >> 16);
        }
        {
            unsigned int* dst = (unsigned int*)sB;
#pragma unroll
            for (int j = 0; j < 16; j++) {
                int idx = tid + j * 256;
                int n = idx >> 4, kp = idx & 15;
                int gn = n0 + n;
                unsigned int v = 0u;
                if (gn < VV) v = ((const unsigned int*)(WfcB + (size_t)gn * 512 + kk))[kp];
                dst[n * 20 + kp] = v;
            }
        }
        __syncthreads();
        short8 af[2], bf[4];
#pragma unroll
        for (int mt = 0; mt < 2; mt++)
            af[mt] = *(const short8*)(sA + (mt * 16 + l16) * 40 + quad * 8);
#pragma unroll
        for (int nt = 0; nt < 4; nt++) {
            int nl = wv * 64 + nt * 16 + l16;
            bf[nt] = *(const short8*)(sB + nl * 40 + quad * 8);
        }
#pragma unroll
        for (int mt = 0; mt < 2; mt++)
#pragma unroll
            for (int nt = 0; nt < 4; nt++)
                acc[mt][nt] = __builtin_amdgcn_mfma_f32_16x16x32_bf16(af[mt], bf[nt], acc[mt][nt], 0, 0, 0);
        __syncthreads();
    }
#pragma unroll
    for (int mt = 0; mt < 2; mt++) {
#pragma unroll
        for (int r = 0; r < 4; r++) {
            int m = mt * 16 + quad * 4 + r;
            bool active = t < dlen[m];
            float* orow = out + OFF_PRED + ((size_t)m * TT + t) * VV;
#pragma unroll
            for (int nt = 0; nt < 4; nt++) {
                int n = n0 + wv * 64 + nt * 16 + l16;
                if (n < VV) orow[n] = active ? (acc[mt][nt][r] + bfc[n]) : 0.f;
            }
        }
    }
}

// ---------------------------------------------------------------- launch
extern "C" void kernel_launch(void* const* d_in, const int* in_sizes, int n_in,
                              void* d_out, int out_size, void* d_ws, size_t ws_size,
                              hipStream_t stream) {
    const float* img   = (const float*)d_in[0];
    const int*   toks  = (const int*)d_in[1];
    const int*   lens  = (const int*)d_in[2];
    const float* Wenc  = (const float*)d_in[3];
    const float* benc  = (const float*)d_in[4];
    const float* Wdec  = (const float*)d_in[5];
    const float* bdec  = (const float*)d_in[6];
    const float* wfull = (const float*)d_in[7];
    // d_in[8] = b_full (scalar 0; softmax-invariant)
    const float* emb   = (const float*)d_in[9];
    const float* Wih   = (const float*)d_in[10];
    const float* bih   = (const float*)d_in[11];
    const float* Whh   = (const float*)d_in[12];
    const float* bhh   = (const float*)d_in[13];
    const float* Wh0   = (const float*)d_in[14];
    const float* bh0   = (const float*)d_in[15];
    const float* Wc0   = (const float*)d_in[16];
    const float* bc0   = (const float*)d_in[17];
    const float* Wbeta = (const float*)d_in[18];
    const float* bbeta = (const float*)d_in[19];
    const float* Wfc   = (const float*)d_in[20];
    const float* bfc   = (const float*)d_in[21];
    float* out = (float*)d_out;

    char* ws = (char*)d_ws;
    int* sidx = (int*)ws;                        ws += 256;
    int* dlen = (int*)ws;                        ws += 256;
    int* cnt  = (int*)ws;                        ws += 256;
    float* cT     = (float*)ws;                  ws += (size_t)DECD * BB * 4;
    float* xT     = (float*)ws;                  ws += (size_t)2560 * BB * 4;
    float* hp     = (float*)ws;                  ws += (size_t)2560 * BB * 4;
    float* s_ws   = (float*)ws;                  ws += (size_t)BB * 200 * 4;
    float* mz_ws  = (float*)ws;                  ws += (size_t)BB * 8 * 2 * 4;
    float* pawe   = (float*)ws;                  ws += (size_t)BB * 8 * 2048 * 4;
    float* gacc   = (float*)ws;                  ws += (size_t)BB * 2048 * 4;
    unsigned short* hBT = (unsigned short*)ws;   ws += (size_t)TT * DECD * BB * 2;
    float* gbase  = (float*)ws;                  ws += (size_t)TT * BB * 2048 * 4;
    unsigned short* WgB = (unsigned short*)ws;   ws += (size_t)2560 * 2048 * 2;
    unsigned int* WhpB  = (unsigned int*)ws;     ws += (size_t)2560 * 512 * 2;
    unsigned int* WihB  = (unsigned int*)ws;     ws += (size_t)2048 * 512 * 2;
    unsigned int* WencB = (unsigned int*)ws;     ws += (size_t)512 * 2048 * 2;
    unsigned int* WfcB  = (unsigned int*)ws;     ws += (size_t)VV * 512 * 2;
    unsigned int* embB  = (unsigned int*)ws;     ws += (size_t)VV * 512 * 2;
    unsigned int* imgB  = (unsigned int*)ws;     ws += (size_t)BB * PP * ENCD * 2;
    unsigned short* encB = (unsigned short*)ws;  ws += (size_t)BB * PP * ATTD * 2;

    int* cnt_b = cnt;
    int* cnt_g = cnt + 32;

    k_sort<<<1, 64, 0, stream>>>(toks, lens, sidx, dlen, cnt, out);
    k_init<<<32, 256, 0, stream>>>(img, sidx, Wh0, bh0, Wc0, bc0, xT, cT);
    k_cvtimg<<<6272, 256, 0, stream>>>(img, sidx, imgB);
    k_cvt4<<<2500, 256, 0, stream>>>(emb, embB);
    k_cvt4<<<2500, 256, 0, stream>>>(Wfc, WfcB);
    k_cvt4<<<512, 256, 0, stream>>>(Wenc, WencB);
    k_cvthp<<<2560, 256, 0, stream>>>(Wdec, Wbeta, WhpB);
    k_cvtwih<<<2048, 256, 0, stream>>>(Wih, WihB);
    k_twgb<<<dim3(80, 64), 256, 0, stream>>>(Wih, Whh, WgB);
    k_genc<<<dim3(196, 2), 256, 0, stream>>>((const unsigned short*)imgB, (const unsigned short*)WencB,
                                             benc, encB);
    k_gemb<<<dim3(51, 8), 256, 0, stream>>>((const unsigned short*)embB, toks, sidx,
                                            (const unsigned short*)WihB, bih, bhh, gbase, gacc);

    for (int t = 0; t < TT; t++) {
        k_hproj<<<256, 256, 0, stream>>>(WhpB, xT, hp);
        k_attn<<<256, 256, 0, stream>>>(t, (const unsigned short*)imgB, encB, hp, bdec, bbeta,
                                        wfull, dlen, s_ws, mz_ws, pawe, xT, cnt_b, out + OFF_ALPHA);
        k_gstep<<<256, 256, 0, stream>>>(t, WgB, xT, gbase, gacc, cT, hBT, dlen, cnt_g);
    }

    k_pred<<<dim3(TT, 40), 256, 0, stream>>>(hBT, (const unsigned short*)WfcB, bfc, dlen, out);
}